// Round 7
// baseline (907.351 us; speedup 1.0000x reference)
//
#include <hip/hip_runtime.h>
#include <hip/hip_bf16.h>

typedef unsigned int u32;
typedef _Float16     f16;
typedef f16   f16x8v __attribute__((ext_vector_type(8)));
typedef float f32x4  __attribute__((ext_vector_type(4)));

#define GX_BYTES ((size_t)65536 * 1024 * 2)

__device__ __forceinline__ float sigm(float x) {
    return __builtin_amdgcn_rcpf(1.0f + __expf(-x));
}
__device__ __forceinline__ float tanh_f(float x) {
    return 1.0f - 2.0f * __builtin_amdgcn_rcpf(__expf(2.0f * x) + 1.0f);
}
__device__ __forceinline__ f16x8v pack8(float4 a, float4 b) {
    f16x8v v;
    v[0] = (f16)a.x; v[1] = (f16)a.y; v[2] = (f16)a.z; v[3] = (f16)a.w;
    v[4] = (f16)b.x; v[5] = (f16)b.y; v[6] = (f16)b.z; v[7] = (f16)b.w;
    return v;
}
// quad_perm DPP (4-lane groups) at VALU speed; CTRL is a compile-time imm.
template <int CTRL>
__device__ __forceinline__ float qperm(float x) {
    int r = __builtin_amdgcn_mov_dpp(__builtin_bit_cast(int, x), CTRL, 0xf, 0xf, true);
    return __builtin_bit_cast(float, r);
}

// ---------------------------------------------------------------------------
// Kernel 1: gates_x = x @ Wg[:, :256]^T + bg  -> f16 [65536][1024]
// (unchanged — plus zeroing the 256 KB mailbox each replay so stale tags
//  can never satisfy this run's polls)
// ---------------------------------------------------------------------------
__global__ __launch_bounds__(256) void gemm_gx(
    const float* __restrict__ X,
    const float* __restrict__ Wf, const float* __restrict__ Wi,
    const float* __restrict__ Wc, const float* __restrict__ Wo,
    const float* __restrict__ bf_, const float* __restrict__ bi_,
    const float* __restrict__ bc_, const float* __restrict__ bo_,
    f16* __restrict__ gx, u32* __restrict__ hx) {
    __shared__ _Float16 As[128 * 40];
    __shared__ _Float16 Bs[128 * 40];
    __shared__ float bias_lds[128];

    const int tid = threadIdx.x;
    const int wgy = blockIdx.y;
    const size_t m0 = (size_t)blockIdx.x * 128;

    if (wgy == 0) {
        const int gid = blockIdx.x * 256 + tid;
        if (gid < 16384) {
            int4 z; z.x = 0; z.y = 0; z.z = 0; z.w = 0;
            ((int4*)hx)[gid] = z;
        }
    }

    const float* Wsel[4] = {Wf, Wi, Wc, Wo};
    const float* bsel[4] = {bf_, bi_, bc_, bo_};
    const float* Wseg = Wsel[wgy >> 1];
    const int row_off = (wgy & 1) * 128;

    if (tid < 128) bias_lds[tid] = bsel[wgy >> 1][row_off + tid];

    const int r  = tid >> 2;
    const int c8 = (tid & 3) * 8;

    const float* Ap0 = X + (m0 + r) * 256 + c8;
    const float* Ap1 = Ap0 + 64 * 256;
    const float* Bp0 = Wseg + (size_t)(row_off + r) * 512 + c8;
    const float* Bp1 = Bp0 + 64 * 512;

    const int lane = tid & 63;
    const int w    = tid >> 6;
    const int wm = w >> 1, wn = w & 1;
    const int col = lane & 15, quad = lane >> 4;

    f32x4 acc[4][4] = {};

    for (int kc = 0; kc < 8; kc++) {
        const int kk = kc * 32;
        float4 a00 = *(const float4*)(Ap0 + kk);
        float4 a01 = *(const float4*)(Ap0 + kk + 4);
        float4 a10 = *(const float4*)(Ap1 + kk);
        float4 a11 = *(const float4*)(Ap1 + kk + 4);
        float4 b00 = *(const float4*)(Bp0 + kk);
        float4 b01 = *(const float4*)(Bp0 + kk + 4);
        float4 b10 = *(const float4*)(Bp1 + kk);
        float4 b11 = *(const float4*)(Bp1 + kk + 4);
        __syncthreads();
        *(f16x8v*)&As[r * 40 + c8]        = pack8(a00, a01);
        *(f16x8v*)&As[(r + 64) * 40 + c8] = pack8(a10, a11);
        *(f16x8v*)&Bs[r * 40 + c8]        = pack8(b00, b01);
        *(f16x8v*)&Bs[(r + 64) * 40 + c8] = pack8(b10, b11);
        __syncthreads();
        f16x8v a[4], b[4];
        #pragma unroll
        for (int i = 0; i < 4; i++)
            a[i] = *(const f16x8v*)&As[(wm * 64 + i * 16 + col) * 40 + quad * 8];
        #pragma unroll
        for (int j = 0; j < 4; j++)
            b[j] = *(const f16x8v*)&Bs[(wn * 64 + j * 16 + col) * 40 + quad * 8];
        #pragma unroll
        for (int i = 0; i < 4; i++)
            #pragma unroll
            for (int j = 0; j < 4; j++)
                acc[i][j] = __builtin_amdgcn_mfma_f32_16x16x32_f16(a[i], b[j], acc[i][j], 0, 0, 0);
    }

    #pragma unroll
    for (int i = 0; i < 4; i++) {
        #pragma unroll
        for (int j = 0; j < 4; j++) {
            #pragma unroll
            for (int rg = 0; rg < 4; rg++) {
                const size_t m = m0 + wm * 64 + i * 16 + quad * 4 + rg;
                const int nl = wn * 64 + j * 16 + col;
                gx[m * 1024 + (size_t)wgy * 128 + nl] = (f16)(acc[i][j][rg] + bias_lds[nl]);
            }
        }
    }
}

// ---------------------------------------------------------------------------
// Kernel 2: 2-batch-packed recurrence, 4-way unit split. 256 WGs x 512 thr
// (1 WG/CU — co-residency guaranteed). WG (p = bb&63, q = bb>>6) owns
// batches {2p, 2p+1} and units [64q, 64q+64).
//
// M=16 A-rows = 8 replicas of batch0 (rows 0-7) + 8 of batch1 (rows 8-15)
// -> replication 8x (was 16x): MFMA halves to 16/wave/step (32/SIMD ~ 620c).
// A-fragment: row = l15 (round-2-validated mapping), so lane supplies
// hbuf[cur][l15>>3][k]. N-cols interleave (unit,gate): col = 4*u' + g ->
// each wave owns 2 tiles (8 units x 4 gates x 2 batches = 16 cells), only
// wB{0,1}[8] = 64 VGPR of weights. C: col=l15 -> (u'=l15>>2, g=l15&3),
// row=quad*4+reg -> batch = quad>>1, reg 0 = replica.
// Gate recombine: 4 adjacent lanes hold F,I,G,O of one cell -> 3x
// mov_dpp(quad_perm) + static selects (no LDS roundtrip, no extra barrier);
// all 8 sharing lanes compute c,h redundantly (identical inputs).
//
// Exchange: fan-in 3, tagged words (h<<16)|(t+1), relaxed agent atomics
// (LLC-serviced), 2-slot double buffer, <=1 word/thread (waves 0-5 poll 64
// words each; waves 6-7 never poll) — the round-2 storm (16 words/thread
// re-loaded) cannot recur. Early-issue at step top, check after phase A
// (own-quarter kt, needs no remote h). Reuse induction generalizes to any
// peer set: X overwrites its tag-(t-1) words with (t+1) only after X got
// every peer's tag-t word, which each peer published only after finishing
// its own tag-(t-1) polls. Mailbox zeroed each replay; spin bounded.
// ---------------------------------------------------------------------------
__global__ __launch_bounds__(512, 2) void lstm_rec(
    const float* __restrict__ Wf, const float* __restrict__ Wi,
    const float* __restrict__ Wc, const float* __restrict__ Wo,
    const f16* __restrict__ gx,
    const float* __restrict__ Wout, const float* __restrict__ bout,
    u32* hx,
    float* __restrict__ out) {
    __shared__ _Float16 hbuf[2][2][256] __attribute__((aligned(16)));

    const int tid  = threadIdx.x;
    const int bb   = blockIdx.x;
    const int p    = bb & 63;         // batch-pair group (batches 2p, 2p+1)
    const int q    = bb >> 6;         // unit-quarter 0..3
    const int w    = tid >> 6;        // wave 0..7
    const int l    = tid & 63;
    const int l15  = l & 15;
    const int quad = l >> 4;
    const int uit  = l15 >> 2;        // unit-in-tile 0..3
    const int g    = l15 & 3;         // this lane's gate
    const int bl   = quad >> 1;       // this lane's batch (0/1 in pair)
    const int arow = l15 >> 3;        // A-row batch this lane supplies

    const int u0 = 64 * q + 8 * w + uit;   // absolute unit, tile j=0
    const int u1 = u0 + 4;                 // tile j=1

    // kt order: 0,1 = own quarter; 2..7 = quarters q+1,q+2,q+3 (wrapped)
    int ktm[8];
    ktm[0] = 2 * q; ktm[1] = 2 * q + 1;
    #pragma unroll
    for (int r = 0; r < 3; r++) {
        const int qr = (q + 1 + r) & 3;
        ktm[2 + 2 * r] = 2 * qr;
        ktm[3 + 2 * r] = 2 * qr + 1;
    }

    // --- register-resident B fragments (static indices only) ---
    const float* Wg_ = (g == 0) ? Wf : (g == 1) ? Wi : (g == 2) ? Wc : Wo;
    f16x8v wB0[8], wB1[8];
    {
        const float* r0 = Wg_ + (size_t)u0 * 512 + 256 + quad * 8;
        const float* r1 = Wg_ + (size_t)u1 * 512 + 256 + quad * 8;
        #pragma unroll
        for (int idx = 0; idx < 8; idx++) {
            const int ko = ktm[idx] * 32;
            float4 x0 = *(const float4*)(r0 + ko);
            float4 x1 = *(const float4*)(r0 + ko + 4);
            wB0[idx] = pack8(x0, x1);
            float4 y0 = *(const float4*)(r1 + ko);
            float4 y1 = *(const float4*)(r1 + ko + 4);
            wB1[idx] = pack8(y0, y1);
        }
    }

    // zero hbuf (h_0 = 0): 1024 f16 = 512 u32
    ((u32*)hbuf)[tid] = 0u;

    // mailbox: per group [2 slots][2 batches][256 units]
    u32* mail = hx + (size_t)p * 1024;

    // poll assignment (waves 0-5 -> 384 words: 3 quarters x 2 b x 64 u)
    const int pollme = (tid < 384);
    int poff = 0, pb = 0, pur = 0;
    if (pollme) {
        const int rq  = tid >> 7;           // remote-quarter rank 0..2
        const int rem = tid & 127;
        pb  = rem >> 6;                     // batch 0/1
        pur = 64 * ((q + 1 + rq) & 3) + (rem & 63);
        poff = pb * 256 + pur;
    }

    // gx: lane reads cells (batch bl, units u0/u1, gate g)
    const f16* gxr = gx + ((size_t)(2 * p + bl) * 512) * 1024 + g * 256 + u0;
    float gx0 = (float)gxr[0];
    float gx1 = (float)gxr[4];

    float c0 = 0.0f, c1 = 0.0f;
    const f32x4 Zc = {0.f, 0.f, 0.f, 0.f};

    __syncthreads();   // h_0 + weights staged

    for (int t = 0; t < 512; t++) {
        const int cur = t & 1;
        const int nxt = cur ^ 1;

        // 1. early-issue partner words (checked after phase A)
        u32 rw = 0;
        if (pollme)
            rw = __hip_atomic_load(mail + cur * 512 + poff,
                                   __ATOMIC_RELAXED, __HIP_MEMORY_SCOPE_AGENT);

        // 2. gx prefetch for next step
        const f16* gn = gxr + (size_t)(t < 511 ? t + 1 : 511) * 1024;
        float pn0 = (float)gn[0];
        float pn1 = (float)gn[4];

        // 3. phase A: own-quarter kt (ktm[0..1]) — no remote dependence
        const _Float16* hb = &hbuf[cur][arow][quad * 8];
        f32x4 a0, a1;
        {
            f16x8v A = *(const f16x8v*)&hb[ktm[0] * 32];
            a0 = __builtin_amdgcn_mfma_f32_16x16x32_f16(A, wB0[0], Zc, 0, 0, 0);
            a1 = __builtin_amdgcn_mfma_f32_16x16x32_f16(A, wB1[0], Zc, 0, 0, 0);
            f16x8v B = *(const f16x8v*)&hb[ktm[1] * 32];
            a0 = __builtin_amdgcn_mfma_f32_16x16x32_f16(B, wB0[1], a0, 0, 0, 0);
            a1 = __builtin_amdgcn_mfma_f32_16x16x32_f16(B, wB1[1], a1, 0, 0, 0);
        }

        // 4. check early words; tight spin only on mismatch; stage to LDS
        if (pollme) {
            const u32 want = (u32)t;
            int spin = 0;
            while ((rw & 0xFFFFu) != want && ++spin < (1 << 20))
                rw = __hip_atomic_load(mail + cur * 512 + poff,
                                       __ATOMIC_RELAXED, __HIP_MEMORY_SCOPE_AGENT);
            hbuf[cur][pb][pur] =
                __builtin_bit_cast(_Float16, (unsigned short)(rw >> 16));
        }
        __syncthreads();   // remote three-quarters of h_t staged

        // 5. phase B: remote kt (ktm[2..7])
        #pragma unroll
        for (int idx = 2; idx < 8; idx++) {
            f16x8v A = *(const f16x8v*)&hb[ktm[idx] * 32];
            a0 = __builtin_amdgcn_mfma_f32_16x16x32_f16(A, wB0[idx], a0, 0, 0, 0);
            a1 = __builtin_amdgcn_mfma_f32_16x16x32_f16(A, wB1[idx], a1, 0, 0, 0);
        }

        // 6. elementwise: recombine the 4 gate-lanes via quad_perm DPP.
        //    xk = value from lane l^k (gate g^k).
        f16 h16a, h16b;
        {
            float pa = a0[0] + gx0;
            float x1 = qperm<177>(pa);   // [1,0,3,2]
            float x2 = qperm<78>(pa);    // [2,3,0,1]
            float x3 = qperm<27>(pa);    // [3,2,1,0]
            float F = (g == 0) ? pa : (g == 1) ? x1 : (g == 2) ? x2 : x3;
            float I = (g == 0) ? x1 : (g == 1) ? pa : (g == 2) ? x3 : x2;
            float G = (g == 0) ? x2 : (g == 1) ? x3 : (g == 2) ? pa : x1;
            float O = (g == 0) ? x3 : (g == 1) ? x2 : (g == 2) ? x1 : pa;
            c0 = c0 * sigm(F) + sigm(I) * tanh_f(G);
            h16a = (f16)(tanh_f(c0) * sigm(O));
        }
        {
            float pa = a1[0] + gx1;
            float x1 = qperm<177>(pa);
            float x2 = qperm<78>(pa);
            float x3 = qperm<27>(pa);
            float F = (g == 0) ? pa : (g == 1) ? x1 : (g == 2) ? x2 : x3;
            float I = (g == 0) ? x1 : (g == 1) ? pa : (g == 2) ? x3 : x2;
            float G = (g == 0) ? x2 : (g == 1) ? x3 : (g == 2) ? pa : x1;
            float O = (g == 0) ? x3 : (g == 1) ? x2 : (g == 2) ? x1 : pa;
            c1 = c1 * sigm(F) + sigm(I) * tanh_f(G);
            h16b = (f16)(tanh_f(c1) * sigm(O));
        }

        // 7. publish + own-LDS write (one writer lane per cell)
        if (g == 0 && (quad & 1) == 0) {
            const u32 tag = (u32)(t + 1);
            u32 w0 = ((u32)__builtin_bit_cast(unsigned short, h16a) << 16) | tag;
            u32 w1 = ((u32)__builtin_bit_cast(unsigned short, h16b) << 16) | tag;
            __hip_atomic_store(mail + nxt * 512 + bl * 256 + u0, w0,
                               __ATOMIC_RELAXED, __HIP_MEMORY_SCOPE_AGENT);
            __hip_atomic_store(mail + nxt * 512 + bl * 256 + u1, w1,
                               __ATOMIC_RELAXED, __HIP_MEMORY_SCOPE_AGENT);
            hbuf[nxt][bl][u0] = h16a;
            hbuf[nxt][bl][u1] = h16b;
        }

        gx0 = pn0; gx1 = pn1;

        __syncthreads();   // own quarter of h_{t+1} visible; guards reuse
    }

    // Complete h_512 (slot 0, tag 512): own quarter already in hbuf[0].
    if (pollme) {
        u32 rw = __hip_atomic_load(mail + 0 * 512 + poff,
                                   __ATOMIC_RELAXED, __HIP_MEMORY_SCOPE_AGENT);
        int spin = 0;
        while ((rw & 0xFFFFu) != 512u && ++spin < (1 << 20))
            rw = __hip_atomic_load(mail + 0 * 512 + poff,
                                   __ATOMIC_RELAXED, __HIP_MEMORY_SCOPE_AGENT);
        hbuf[0][pb][pur] =
            __builtin_bit_cast(_Float16, (unsigned short)(rw >> 16));
    }
    __syncthreads();

    // out[2p+b, 32q:32q+32] = h_512 @ Wout^T + bout
    if (tid < 64) {
        const int b_loc = tid >> 5;
        const int o     = 32 * q + (tid & 31);
        float accv = bout[o];
        const _Float16* hr = &hbuf[0][b_loc][0];
        const float* wr = Wout + (size_t)o * 256;
        for (int k0 = 0; k0 < 256; k0 += 8) {
            f16x8v hv = *(const f16x8v*)&hr[k0];
            float4 w0 = *(const float4*)(wr + k0);
            float4 w1 = *(const float4*)(wr + k0 + 4);
            accv += w0.x * (float)hv[0] + w0.y * (float)hv[1]
                  + w0.z * (float)hv[2] + w0.w * (float)hv[3]
                  + w1.x * (float)hv[4] + w1.y * (float)hv[5]
                  + w1.z * (float)hv[6] + w1.w * (float)hv[7];
        }
        out[(size_t)(2 * p + b_loc) * 128 + o] = accv;
    }
}

extern "C" void kernel_launch(void* const* d_in, const int* in_sizes, int n_in,
                              void* d_out, int out_size, void* d_ws, size_t ws_size,
                              hipStream_t stream) {
    const float* x    = (const float*)d_in[0];
    const float* Wf   = (const float*)d_in[1];
    const float* bfv  = (const float*)d_in[2];
    const float* Wi   = (const float*)d_in[3];
    const float* biv  = (const float*)d_in[4];
    const float* Wc   = (const float*)d_in[5];
    const float* bcv  = (const float*)d_in[6];
    const float* Wo   = (const float*)d_in[7];
    const float* bov  = (const float*)d_in[8];
    const float* Wout = (const float*)d_in[9];
    const float* bout = (const float*)d_in[10];

    f16* gx = (f16*)d_ws;
    u32* hx = (u32*)((char*)d_ws + GX_BYTES);   // 256 KB mailbox after gx

    gemm_gx<<<dim3(512, 8), 256, 0, stream>>>(x, Wf, Wi, Wc, Wo, bfv, biv, bcv, bov, gx, hx);
    lstm_rec<<<256, 512, 0, stream>>>(Wf, Wi, Wc, Wo, gx, Wout, bout, hx, (float*)d_out);
}

// Round 8
// 834.914 us; speedup vs baseline: 1.0868x; 1.0868x over previous
//
#include <hip/hip_runtime.h>
#include <hip/hip_bf16.h>

typedef unsigned int u32;
typedef _Float16     f16;
typedef f16   f16x8v __attribute__((ext_vector_type(8)));
typedef float f32x4  __attribute__((ext_vector_type(4)));

#define GX_BYTES ((size_t)65536 * 1024 * 2)

__device__ __forceinline__ float sigm(float x) {
    return __builtin_amdgcn_rcpf(1.0f + __expf(-x));
}
__device__ __forceinline__ float tanh_f(float x) {
    return 1.0f - 2.0f * __builtin_amdgcn_rcpf(__expf(2.0f * x) + 1.0f);
}
__device__ __forceinline__ f16x8v pack8(float4 a, float4 b) {
    f16x8v v;
    v[0] = (f16)a.x; v[1] = (f16)a.y; v[2] = (f16)a.z; v[3] = (f16)a.w;
    v[4] = (f16)b.x; v[5] = (f16)b.y; v[6] = (f16)b.z; v[7] = (f16)b.w;
    return v;
}

// ---------------------------------------------------------------------------
// Kernel 1: gates_x = x @ Wg[:, :256]^T + bg  -> f16 [65536][1024]
// (unchanged — plus zeroing the 256 KB mailbox each replay so stale tags
//  can never satisfy this run's polls)
// ---------------------------------------------------------------------------
__global__ __launch_bounds__(256) void gemm_gx(
    const float* __restrict__ X,
    const float* __restrict__ Wf, const float* __restrict__ Wi,
    const float* __restrict__ Wc, const float* __restrict__ Wo,
    const float* __restrict__ bf_, const float* __restrict__ bi_,
    const float* __restrict__ bc_, const float* __restrict__ bo_,
    f16* __restrict__ gx, u32* __restrict__ hx) {
    __shared__ _Float16 As[128 * 40];
    __shared__ _Float16 Bs[128 * 40];
    __shared__ float bias_lds[128];

    const int tid = threadIdx.x;
    const int wgy = blockIdx.y;
    const size_t m0 = (size_t)blockIdx.x * 128;

    if (wgy == 0) {
        const int gid = blockIdx.x * 256 + tid;
        if (gid < 16384) {
            int4 z; z.x = 0; z.y = 0; z.z = 0; z.w = 0;
            ((int4*)hx)[gid] = z;
        }
    }

    const float* Wsel[4] = {Wf, Wi, Wc, Wo};
    const float* bsel[4] = {bf_, bi_, bc_, bo_};
    const float* Wseg = Wsel[wgy >> 1];
    const int row_off = (wgy & 1) * 128;

    if (tid < 128) bias_lds[tid] = bsel[wgy >> 1][row_off + tid];

    const int r  = tid >> 2;
    const int c8 = (tid & 3) * 8;

    const float* Ap0 = X + (m0 + r) * 256 + c8;
    const float* Ap1 = Ap0 + 64 * 256;
    const float* Bp0 = Wseg + (size_t)(row_off + r) * 512 + c8;
    const float* Bp1 = Bp0 + 64 * 512;

    const int lane = tid & 63;
    const int w    = tid >> 6;
    const int wm = w >> 1, wn = w & 1;
    const int col = lane & 15, quad = lane >> 4;

    f32x4 acc[4][4] = {};

    for (int kc = 0; kc < 8; kc++) {
        const int kk = kc * 32;
        float4 a00 = *(const float4*)(Ap0 + kk);
        float4 a01 = *(const float4*)(Ap0 + kk + 4);
        float4 a10 = *(const float4*)(Ap1 + kk);
        float4 a11 = *(const float4*)(Ap1 + kk + 4);
        float4 b00 = *(const float4*)(Bp0 + kk);
        float4 b01 = *(const float4*)(Bp0 + kk + 4);
        float4 b10 = *(const float4*)(Bp1 + kk);
        float4 b11 = *(const float4*)(Bp1 + kk + 4);
        __syncthreads();
        *(f16x8v*)&As[r * 40 + c8]        = pack8(a00, a01);
        *(f16x8v*)&As[(r + 64) * 40 + c8] = pack8(a10, a11);
        *(f16x8v*)&Bs[r * 40 + c8]        = pack8(b00, b01);
        *(f16x8v*)&Bs[(r + 64) * 40 + c8] = pack8(b10, b11);
        __syncthreads();
        f16x8v a[4], b[4];
        #pragma unroll
        for (int i = 0; i < 4; i++)
            a[i] = *(const f16x8v*)&As[(wm * 64 + i * 16 + col) * 40 + quad * 8];
        #pragma unroll
        for (int j = 0; j < 4; j++)
            b[j] = *(const f16x8v*)&Bs[(wn * 64 + j * 16 + col) * 40 + quad * 8];
        #pragma unroll
        for (int i = 0; i < 4; i++)
            #pragma unroll
            for (int j = 0; j < 4; j++)
                acc[i][j] = __builtin_amdgcn_mfma_f32_16x16x32_f16(a[i], b[j], acc[i][j], 0, 0, 0);
    }

    #pragma unroll
    for (int i = 0; i < 4; i++) {
        #pragma unroll
        for (int j = 0; j < 4; j++) {
            #pragma unroll
            for (int rg = 0; rg < 4; rg++) {
                const size_t m = m0 + wm * 64 + i * 16 + quad * 4 + rg;
                const int nl = wn * 64 + j * 16 + col;
                gx[m * 1024 + (size_t)wgy * 128 + nl] = (f16)(acc[i][j][rg] + bias_lds[nl]);
            }
        }
    }
}

// ---------------------------------------------------------------------------
// Kernel 2: round-5 math, re-tiled for CU-level overlap. 512 WGs x 256 thr,
// __launch_bounds__(256,2) -> 2 co-resident WGs/CU, 2 waves/SIMD from
// DIFFERENT batches (b=blk>>2, j=blk&3: blocks i and i+256 share a CU and
// serve batches b and b+64 — independent exchange groups). When one WG
// sits in its spin/barrier (~800 cyc exposed LLC RTT in round 5), the
// other's MFMAs issue on the same SIMD — the matrix pipe stays fed.
//
// WG (b, j) owns units [64j, 64j+64); wave w owns 16 units x 4 gates =
// 4 tiles x 8 kt = 32 MFMA/step. kt order ktm[] = own quarter first
// (phase A, no remote dep), then the 3 remote quarters (phase B). ktm is
// runtime (j) but appears ONLY in addresses; register arrays use the
// static unroll index (rule #20). A-reads are quad-broadcast (round 5's
// 0-conflict pattern). One batch per WG -> single elementwise chain.
//
// Mailbox: per batch [2 slots][256 units] tagged words (h<<16)|(t+1),
// relaxed agent atomics, 2-slot double buffer, fan-in 3 with <=1
// word/thread (tid<192). Early-issue at step top, check after phase A,
// tight spin on mismatch. Reuse induction as proven. Zeroed each replay;
// t=0 poll matches tag-0 zeros (= h_0); spin bounded.
// ---------------------------------------------------------------------------
__global__ __launch_bounds__(256, 2) void lstm_rec(
    const float* __restrict__ Wf, const float* __restrict__ Wi,
    const float* __restrict__ Wc, const float* __restrict__ Wo,
    const f16* __restrict__ gx,
    const float* __restrict__ Wout, const float* __restrict__ bout,
    u32* hx,
    float* __restrict__ out) {
    __shared__ _Float16 hbuf[2][256] __attribute__((aligned(16)));

    const int tid  = threadIdx.x;
    const int bb   = blockIdx.x;
    const int b    = bb >> 2;         // batch 0..127
    const int j    = bb & 3;          // unit-quarter 0..3
    const int w    = tid >> 6;        // wave 0..3
    const int l    = tid & 63;
    const int l15  = l & 15;
    const int quad = l >> 4;

    const int u = 64 * j + 16 * w + l15;   // this lane's unit

    // kt order: own quarter first, then remote quarters (wrapped)
    int ktm[8];
    ktm[0] = 2 * j; ktm[1] = 2 * j + 1;
    #pragma unroll
    for (int r = 0; r < 3; r++) {
        const int qr = (j + 1 + r) & 3;
        ktm[2 + 2 * r] = 2 * qr;
        ktm[3 + 2 * r] = 2 * qr + 1;
    }

    // --- register-resident B fragments (static reg indices only) ---
    f16x8v wB[4][8];
    {
        const float* gp[4] = {Wf, Wi, Wc, Wo};
        #pragma unroll
        for (int g = 0; g < 4; g++) {
            const float* row = gp[g] + (size_t)u * 512 + 256 + quad * 8;
            #pragma unroll
            for (int idx = 0; idx < 8; idx++) {
                const int ko = ktm[idx] * 32;
                float4 x0 = *(const float4*)(row + ko);
                float4 x1 = *(const float4*)(row + ko + 4);
                wB[g][idx] = pack8(x0, x1);
            }
        }
    }

    // h_0 = 0 (zero both buffers: 512 f16 = 256 u32)
    ((u32*)hbuf)[tid] = 0u;

    u32* mail = hx + (size_t)b * 512;          // [slot][256 units]

    // poll assignment: tid<192 covers the 3 remote quarters, 1 word each
    const int pollme = (tid < 192);
    const int pua = tid + (tid >= 64 * j ? 64 : 0);   // remote unit id

    const f16* gxr = gx + (size_t)b * 512 * 1024 + u;
    float pf  = (float)gxr[0];
    float pi_ = (float)gxr[256];
    float pg  = (float)gxr[512];
    float po  = (float)gxr[768];

    float c = 0.0f;
    const f32x4 Zc = {0.f, 0.f, 0.f, 0.f};

    __syncthreads();   // h_0 visible

    for (int t = 0; t < 512; t++) {
        const int cur = t & 1;
        const int nxt = cur ^ 1;

        // 1. early-issue the remote-word load (checked after phase A)
        u32 rw = 0;
        if (pollme)
            rw = __hip_atomic_load(mail + cur * 256 + pua,
                                   __ATOMIC_RELAXED, __HIP_MEMORY_SCOPE_AGENT);

        // 2. gx prefetch for next step
        float pnf, pni, png, pno;
        {
            const f16* gn = gxr + (size_t)(t < 511 ? t + 1 : 511) * 1024;
            pnf = (float)gn[0];
            pni = (float)gn[256];
            png = (float)gn[512];
            pno = (float)gn[768];
        }

        // 3. phase A: own-quarter kt (ktm[0..1]) — no remote dependence
        f32x4 acc[4];
        {
            f16x8v A = *(const f16x8v*)&hbuf[cur][ktm[0] * 32 + quad * 8];
            #pragma unroll
            for (int g = 0; g < 4; g++)
                acc[g] = __builtin_amdgcn_mfma_f32_16x16x32_f16(A, wB[g][0], Zc, 0, 0, 0);
            f16x8v B = *(const f16x8v*)&hbuf[cur][ktm[1] * 32 + quad * 8];
            #pragma unroll
            for (int g = 0; g < 4; g++)
                acc[g] = __builtin_amdgcn_mfma_f32_16x16x32_f16(B, wB[g][1], acc[g], 0, 0, 0);
        }

        // 4. check early words; tight spin only on mismatch; stage to LDS
        if (pollme) {
            const u32 want = (u32)t;
            int spin = 0;
            while ((rw & 0xFFFFu) != want && ++spin < (1 << 20))
                rw = __hip_atomic_load(mail + cur * 256 + pua,
                                       __ATOMIC_RELAXED, __HIP_MEMORY_SCOPE_AGENT);
            hbuf[cur][pua] =
                __builtin_bit_cast(_Float16, (unsigned short)(rw >> 16));
        }
        __syncthreads();   // remote three-quarters of h_t staged

        // 5. phase B: remote kt (ktm[2..7])
        #pragma unroll
        for (int idx = 2; idx < 8; idx++) {
            f16x8v A = *(const f16x8v*)&hbuf[cur][ktm[idx] * 32 + quad * 8];
            #pragma unroll
            for (int g = 0; g < 4; g++)
                acc[g] = __builtin_amdgcn_mfma_f32_16x16x32_f16(A, wB[g][idx], acc[g], 0, 0, 0);
        }

        // 6. elementwise (rows replicated -> reg 0 is this lane's unit)
        float F = pf + acc[0][0];
        float I = pi_ + acc[1][0];
        float G = pg + acc[2][0];
        float O = po + acc[3][0];
        float sf = sigm(F), si = sigm(I), so = sigm(O);
        float tg = tanh_f(G);
        c = c * sf + si * tg;
        float h = tanh_f(c) * so;

        const f16 h16v = (f16)h;
        if (quad == 0) {
            u32 word = ((u32)__builtin_bit_cast(unsigned short, h16v) << 16)
                     | (u32)(t + 1);
            __hip_atomic_store(mail + nxt * 256 + u, word,
                               __ATOMIC_RELAXED, __HIP_MEMORY_SCOPE_AGENT);
            hbuf[nxt][u] = h16v;    // own quarter for next step
        }

        pf = pnf; pi_ = pni; pg = png; po = pno;

        __syncthreads();   // own quarter of h_{t+1} visible; guards reuse
    }

    // Complete h_512 (slot 0, tag 512): own quarter already in hbuf[0].
    if (pollme) {
        u32 rw = __hip_atomic_load(mail + 0 * 256 + pua,
                                   __ATOMIC_RELAXED, __HIP_MEMORY_SCOPE_AGENT);
        int spin = 0;
        while ((rw & 0xFFFFu) != 512u && ++spin < (1 << 20))
            rw = __hip_atomic_load(mail + 0 * 256 + pua,
                                   __ATOMIC_RELAXED, __HIP_MEMORY_SCOPE_AGENT);
        hbuf[0][pua] =
            __builtin_bit_cast(_Float16, (unsigned short)(rw >> 16));
    }
    __syncthreads();

    // out[b, 32j:32j+32] = h_512 @ Wout^T + bout
    if (tid < 32) {
        const int o = 32 * j + tid;
        float accv = bout[o];
        const float* wr = Wout + (size_t)o * 256;
        for (int k0 = 0; k0 < 256; k0 += 8) {
            f16x8v hv = *(const f16x8v*)&hbuf[0][k0];
            float4 w0 = *(const float4*)(wr + k0);
            float4 w1 = *(const float4*)(wr + k0 + 4);
            accv += w0.x * (float)hv[0] + w0.y * (float)hv[1]
                  + w0.z * (float)hv[2] + w0.w * (float)hv[3]
                  + w1.x * (float)hv[4] + w1.y * (float)hv[5]
                  + w1.z * (float)hv[6] + w1.w * (float)hv[7];
        }
        out[(size_t)b * 128 + o] = accv;
    }
}

extern "C" void kernel_launch(void* const* d_in, const int* in_sizes, int n_in,
                              void* d_out, int out_size, void* d_ws, size_t ws_size,
                              hipStream_t stream) {
    const float* x    = (const float*)d_in[0];
    const float* Wf   = (const float*)d_in[1];
    const float* bfv  = (const float*)d_in[2];
    const float* Wi   = (const float*)d_in[3];
    const float* biv  = (const float*)d_in[4];
    const float* Wc   = (const float*)d_in[5];
    const float* bcv  = (const float*)d_in[6];
    const float* Wo   = (const float*)d_in[7];
    const float* bov  = (const float*)d_in[8];
    const float* Wout = (const float*)d_in[9];
    const float* bout = (const float*)d_in[10];

    f16* gx = (f16*)d_ws;
    u32* hx = (u32*)((char*)d_ws + GX_BYTES);   // 256 KB mailbox after gx

    gemm_gx<<<dim3(512, 8), 256, 0, stream>>>(x, Wf, Wi, Wc, Wo, bfv, biv, bcv, bov, gx, hx);
    lstm_rec<<<512, 256, 0, stream>>>(Wf, Wi, Wc, Wo, gx, Wout, bout, hx, (float*)d_out);
}